// Round 17
// baseline (162.932 us; speedup 1.0000x reference)
//
#include <hip/hip_runtime.h>
#include <math.h>

#define LSEQ 4096
#define NC   4096      // complex FFT length (real length 8192 via packing)
#define NM   64
#define NBH  4096

__device__ __forceinline__ float2 cmulf(float2 a, float2 b) {
  return make_float2(a.x*b.x - a.y*b.y, a.x*b.y + a.y*b.x);
}
// a * conj(b)
__device__ __forceinline__ float2 cmulc(float2 a, float2 b) {
  return make_float2(a.x*b.x + a.y*b.y, a.y*b.x - a.x*b.y);
}
__device__ __forceinline__ float2 caddf(float2 a, float2 b){ return make_float2(a.x+b.x, a.y+b.y); }
__device__ __forceinline__ float2 csubf(float2 a, float2 b){ return make_float2(a.x-b.x, a.y-b.y); }

// base-8 digit reverse of a 9-bit value (involution)
__host__ __device__ __forceinline__ int rev3(int x){ return ((x&7)<<6) | (x&56) | ((x>>6)&7); }

// swizzle for 4096-elem float2 LDS: b0-2 ^= b3-5, b3-5 ^= b6-8 (original bits; triangular,
// bijective). Audited: strides 512/64/8/1 all land at 16 bank-pairs x 4 lanes = b64 floor.
__device__ __forceinline__ int ZS4(int i){
  return i ^ ((i>>3)&7) ^ (((i>>6)&7)<<3);
}

// ---- 8-point DFT, DIF r2 cascade, outputs natural order (r15-validated) ----
__device__ __forceinline__ void dft8_fwd(float2 x[8]) {
  const float RC = 0.7071067811865476f;
  float2 u0=caddf(x[0],x[4]), v0=csubf(x[0],x[4]);
  float2 u1=caddf(x[1],x[5]), d1=csubf(x[1],x[5]);
  float2 u2=caddf(x[2],x[6]), d2=csubf(x[2],x[6]);
  float2 u3=caddf(x[3],x[7]), d3=csubf(x[3],x[7]);
  float2 v1 = make_float2(RC*(d1.x + d1.y), RC*(d1.y - d1.x));
  float2 v2 = make_float2(d2.y, -d2.x);
  float2 v3 = make_float2(RC*(d3.y - d3.x), -RC*(d3.x + d3.y));
  float2 p0=caddf(u0,u2), q0=csubf(u0,u2);
  float2 p1=caddf(u1,u3), qt=csubf(u1,u3);
  float2 q1 = make_float2(qt.y, -qt.x);
  float2 r0=caddf(v0,v2), s0=csubf(v0,v2);
  float2 r1=caddf(v1,v3), st=csubf(v1,v3);
  float2 s1 = make_float2(st.y, -st.x);
  x[0]=caddf(p0,p1); x[4]=csubf(p0,p1);
  x[2]=caddf(q0,q1); x[6]=csubf(q0,q1);
  x[1]=caddf(r0,r1); x[5]=csubf(r0,r1);
  x[3]=caddf(s0,s1); x[7]=csubf(s0,s1);
}
__device__ __forceinline__ void dft8_inv(float2 x[8]) {
  const float RC = 0.7071067811865476f;
  float2 p0=caddf(x[0],x[4]), p1=csubf(x[0],x[4]);
  float2 q0=caddf(x[2],x[6]), q1=csubf(x[2],x[6]);
  float2 r0=caddf(x[1],x[5]), r1=csubf(x[1],x[5]);
  float2 s0=caddf(x[3],x[7]), s1=csubf(x[3],x[7]);
  float2 q1i = make_float2(-q1.y, q1.x);
  float2 s1i = make_float2(-s1.y, s1.x);
  float2 u0=caddf(p0,q0), u2=csubf(p0,q0);
  float2 u1=caddf(p1,q1i), u3=csubf(p1,q1i);
  float2 v0=caddf(r0,s0), v2=csubf(r0,s0);
  float2 v1=caddf(r1,s1i), v3=csubf(r1,s1i);
  float2 w1 = make_float2(RC*(v1.x - v1.y), RC*(v1.x + v1.y));
  float2 w2 = make_float2(-v2.y, v2.x);
  float2 w3 = make_float2(-RC*(v3.x + v3.y), RC*(v3.x - v3.y));
  x[0]=caddf(u0,v0); x[4]=csubf(u0,v0);
  x[1]=caddf(u1,w1); x[5]=csubf(u1,w1);
  x[2]=caddf(u2,w2); x[6]=csubf(u2,w2);
  x[3]=caddf(u3,w3); x[7]=csubf(u3,w3);
}

// table twiddles: T[q*J+j] packs (w_{2q+1}, w_{2q+2})
__device__ __forceinline__ void tw_fwd(float2 x[8], const float4* __restrict__ T, int J, int j) {
  float4 a0 = T[j],       a1 = T[J+j];
  x[1]=cmulf(x[1],make_float2(a0.x,a0.y));
  x[2]=cmulf(x[2],make_float2(a0.z,a0.w));
  x[3]=cmulf(x[3],make_float2(a1.x,a1.y));
  x[4]=cmulf(x[4],make_float2(a1.z,a1.w));
  float4 a2 = T[2*J+j],   a3 = T[3*J+j];
  x[5]=cmulf(x[5],make_float2(a2.x,a2.y));
  x[6]=cmulf(x[6],make_float2(a2.z,a2.w));
  x[7]=cmulf(x[7],make_float2(a3.x,a3.y));
}
__device__ __forceinline__ void tw_inv(float2 x[8], const float4* __restrict__ T, int J, int j) {
  float4 a0 = T[j],       a1 = T[J+j];
  x[1]=cmulc(x[1],make_float2(a0.x,a0.y));
  x[2]=cmulc(x[2],make_float2(a0.z,a0.w));
  x[3]=cmulc(x[3],make_float2(a1.x,a1.y));
  x[4]=cmulc(x[4],make_float2(a1.z,a1.w));
  float4 a2 = T[2*J+j],   a3 = T[3*J+j];
  x[5]=cmulc(x[5],make_float2(a2.x,a2.y));
  x[6]=cmulc(x[6],make_float2(a2.z,a2.w));
  x[7]=cmulc(x[7],make_float2(a3.x,a3.y));
}

// W16^m = exp(-2*pi*i*m/16)  (r15-validated values) -- used for W8192^{512m}
#define DECL_W16C \
  const float2 W16C[8] = { make_float2(1.f,0.f), \
    make_float2(0.9238795325112867f,-0.3826834323650898f), \
    make_float2(0.7071067811865476f,-0.7071067811865476f), \
    make_float2(0.3826834323650898f,-0.9238795325112867f), \
    make_float2(0.f,-1.f), \
    make_float2(-0.3826834323650898f,-0.9238795325112867f), \
    make_float2(-0.7071067811865476f,-0.7071067811865476f), \
    make_float2(-0.9238795325112867f,-0.3826834323650898f) };

__device__ __forceinline__ float2 W8192e(long long e) {
  double ang = -2.0*M_PI*(double)(e & 8191)/8192.0;
  return make_float2((float)cos(ang), (float)sin(ang));
}

// ---------------- prep1: cauchy (blocks 0..63, r16-validated) + tables (64..75) ----------
// Tables: T1[4][512] (W4096^{jm}), T2[4][64] (W512^{jm}), T3[4][8] (W64^{jm}),
//         wb[512] = W8192^{rev3(t)}, mir[512] = rev3(512 - rev3(t))  (mir[0]=0).
__global__ void prep1_kernel(const float* __restrict__ Lre, const float* __restrict__ Lim,
                             const float* __restrict__ Pre, const float* __restrict__ Pim,
                             const float* __restrict__ Bre, const float* __restrict__ Bim,
                             const float* __restrict__ Cri, const float* __restrict__ lstep,
                             float2* __restrict__ a_out,
                             float4* __restrict__ T1, float4* __restrict__ T2,
                             float4* __restrict__ T3, float2* __restrict__ wb,
                             int* __restrict__ mir) {
  if (blockIdx.x >= 64) {
    int idx = (blockIdx.x - 64)*blockDim.x + threadIdx.x;
    if (idx < 2048) {                      // T1: sub-size 4096
      int q = idx >> 9, j = idx & 511;
      float2 wa = W8192e(2LL*j*(2*q+1));
      float2 wbv = W8192e(2LL*j*(2*q+2));
      T1[(q<<9)+j] = make_float4(wa.x, wa.y, wbv.x, wbv.y);
    } else if (idx < 2304) {               // T2: sub-size 512
      int r = idx - 2048; int q = r >> 6, j = r & 63;
      float2 wa = W8192e(16LL*j*(2*q+1));
      float2 wbv = W8192e(16LL*j*(2*q+2));
      T2[(q<<6)+j] = make_float4(wa.x, wa.y, wbv.x, wbv.y);
    } else if (idx < 2336) {               // T3: sub-size 64
      int r = idx - 2304; int q = r >> 3, j = r & 7;
      float2 wa = W8192e(128LL*j*(2*q+1));
      float2 wbv = W8192e(128LL*j*(2*q+2));
      T3[(q<<3)+j] = make_float4(wa.x, wa.y, wbv.x, wbv.y);
    } else if (idx < 2848) {               // wb + mir
      int t = idx - 2336;
      int r = rev3(t);
      wb[t] = W8192e((long long)r);
      mir[t] = (r == 0) ? 0 : rev3(512 - r);
    }
    return;
  }
  // ---- cauchy: 4 sub-lanes per k (r16-validated) ----
  const int tid = threadIdx.x;
  const int k = (blockIdx.x << 6) + (tid >> 2);
  const int sub = tid & 3;
  double step = exp((double)lstep[0]);
  double ang = -2.0*M_PI*(double)k/(double)LSEQ;
  double wr = cos(ang), wi = sin(ang);
  double nr = 1.0 - wr, ni = -wi;
  double dr = 1.0 + wr, di = wi;
  double dn = dr*dr + di*di;
  double gre = (2.0/step) * (nr*dr + ni*di)/dn;
  double gim = (2.0/step) * (ni*dr - nr*di)/dn;
  double cre = 2.0*dr/dn, cim = -2.0*di/dn;
  double k00r=0,k00i=0,k01r=0,k01i=0,k10r=0,k10i=0,k11r=0,k11i=0;
  for (int n = sub; n < NM; n += 4) {
    double lre = Lre[n], lim = Lim[n];
    double pre = Pre[n], pim = Pim[n];
    double bre = Bre[n], bim = Bim[n];
    double ccr = Cri[2*n], cci = Cri[2*n+1];
    double er = gre - lre, ei = gim - lim;
    double inv = 1.0/(er*er + ei*ei);
    double ir =  er*inv, ii = -ei*inv;
    double v00r = ccr*bre + cci*bim, v00i = ccr*bim - cci*bre;
    double v01r = ccr*pre + cci*pim, v01i = ccr*pim - cci*pre;
    double v10r = pre*bre + pim*bim, v10i = pre*bim - pim*bre;
    double v11r = pre*pre + pim*pim, v11i = 0.0;
    k00r += v00r*ir - v00i*ii;  k00i += v00r*ii + v00i*ir;
    k01r += v01r*ir - v01i*ii;  k01i += v01r*ii + v01i*ir;
    k10r += v10r*ir - v10i*ii;  k10i += v10r*ii + v10i*ir;
    k11r += v11r*ir - v11i*ii;  k11i += v11r*ii + v11i*ir;
  }
  #pragma unroll
  for (int d = 1; d <= 2; d <<= 1) {
    k00r += __shfl_xor(k00r, d);  k00i += __shfl_xor(k00i, d);
    k01r += __shfl_xor(k01r, d);  k01i += __shfl_xor(k01i, d);
    k10r += __shfl_xor(k10r, d);  k10i += __shfl_xor(k10i, d);
    k11r += __shfl_xor(k11r, d);  k11i += __shfl_xor(k11i, d);
  }
  if (sub == 0) {
    double numr = k01r*k10r - k01i*k10i, numi = k01r*k10i + k01i*k10r;
    double der = 1.0 + k11r, dei = k11i;
    double dinv = 1.0/(der*der + dei*dei);
    double qr = (numr*der + numi*dei)*dinv;
    double qi = (numi*der - numr*dei)*dinv;
    double tr = k00r - qr, ti = k00i - qi;
    double ar = cre*tr - cim*ti, ai = cre*ti + cim*tr;
    a_out[k] = make_float2((float)ar, (float)ai);
  }
}

// ---------------- prep: K[l] = Re(IDFT_L(a))[l], 64 lanes per output (validated) ----------
__global__ void ktime_kernel(const float2* __restrict__ a, float* __restrict__ K) {
  int lane = threadIdx.x & 63;
  int l = blockIdx.x * (blockDim.x >> 6) + (threadIdx.x >> 6);
  if (l >= LSEQ) return;
  double ang0 = 2.0*M_PI*(double)((l*lane) & (LSEQ-1))/(double)LSEQ;
  double tr = cos(ang0), ti = sin(ang0);
  double ang1 = 2.0*M_PI*(double)(l & 63)/64.0;
  double wr = cos(ang1), wi = sin(ang1);
  double acc = 0.0;
  for (int k = 0; k < 64; k++) {
    float2 ak = a[lane + (k << 6)];
    acc += (double)ak.x*tr - (double)ak.y*ti;
    double ntr = tr*wr - ti*wi;
    ti = tr*wi + ti*wr;
    tr = ntr;
  }
  for (int off = 32; off > 0; off >>= 1) acc += __shfl_down(acc, off);
  if (lane == 0) K[l] = (float)(acc/(double)LSEQ);
}

// ---------------- prep: H[k] = sum_l K[l] W8192^{kl}, k=0..4096 (r6-validated) -----------
__global__ void hspec_kernel(const float* __restrict__ K, float2* __restrict__ H) {
  int lane = threadIdx.x & 63;
  int k = blockIdx.x * (blockDim.x >> 6) + (threadIdx.x >> 6);
  if (k > NC) return;
  int m0 = (k*lane) & 8191;
  double a0 = -2.0*M_PI*(double)m0/8192.0;
  double cr = cos(a0), ci = sin(a0);
  int ms = (k << 6) & 8191;
  double as = -2.0*M_PI*(double)ms/8192.0;
  double sr = cos(as), si = sin(as);
  double accr = 0.0, acci = 0.0;
  for (int j = 0; j < 64; j++) {
    double Kv = (double)K[lane + (j << 6)];
    accr += Kv*cr; acci += Kv*ci;
    double nr2 = cr*sr - ci*si;
    ci = cr*si + ci*sr; cr = nr2;
  }
  for (int off = 32; off > 0; off >>= 1) {
    accr += __shfl_down(accr, off);
    acci += __shfl_down(acci, off);
  }
  if (lane == 0) H[k] = make_float2((float)accr, (float)acci);
}

// ---------------- prep: kda/kdb per in-place position; k(p) = (p&7)*512 + rev3(p>>3) -----
__global__ void kdmap_kernel(const float2* __restrict__ H, const float* __restrict__ Dp,
                             float2* __restrict__ kda, float2* __restrict__ kdb) {
  int p = blockIdx.x*blockDim.x + threadIdx.x;
  if (p >= NC) return;
  int k = ((p & 7) << 9) | rev3(p >> 3);
  const float s = 1.0f/16384.0f;
  float Dv = Dp[0];
  float2 ha = H[k], hb = H[NC - k];
  kda[p] = make_float2((ha.x + Dv)*s, ha.y*s);
  kdb[p] = make_float2((hb.x + Dv)*s, hb.y*s);
}

// ---------------- main: 1 row/block, packed real-8192 as complex-4096, radix-8^4 ----------
// 512 thr x 8 elems, LDS 32KB (half of r16) -> 4 blocks/CU class; (512,4) -> VGPR cap 64.
// Chain: P1(s=512) | P2(s=64) | P3(s=8) | P4(s=1)+publish | untangle (mirrors streamed
// from LDS, r6-validated formula) | P4i | P3i | P2i | P1i. 4 full + 4 wave barriers
// (P2<->P3<->P4 ownership is aligned-8-thread-group = same-wave).
__global__ __launch_bounds__(512, 4)
void conv4_kernel(const float* __restrict__ u,
                  const float4* __restrict__ T1, const float4* __restrict__ T2,
                  const float4* __restrict__ T3, const float2* __restrict__ wbt,
                  const int* __restrict__ mir, const float2* __restrict__ kda,
                  const float2* __restrict__ kdb, float* __restrict__ out) {
  __shared__ float2 z[NC];
  const int T = threadIdx.x;
  const float2* u2 = (const float2*)(u + (size_t)blockIdx.x*LSEQ);
  float2 x[8];
  // ---- P1 fwd: s=512; packed load z[n]=u[2n]+i*u[2n+1], n>=2048 zero ----
  {
    #pragma unroll
    for (int m = 0; m < 4; m++) x[m] = u2[T + (m<<9)];
    #pragma unroll
    for (int m = 4; m < 8; m++) x[m] = make_float2(0.f, 0.f);
    dft8_fwd(x); tw_fwd(x, T1, 512, T);
    #pragma unroll
    for (int m = 0; m < 8; m++) z[ZS4(T + (m<<9))] = x[m];
  }
  __syncthreads();
  // ---- P2 fwd: s=64 ----
  const int j2 = T & 63, g2 = (T>>6)<<9;
  {
    #pragma unroll
    for (int m = 0; m < 8; m++) x[m] = z[ZS4(g2 + j2 + (m<<6))];
    dft8_fwd(x); tw_fwd(x, T2, 64, j2);
    #pragma unroll
    for (int m = 0; m < 8; m++) z[ZS4(g2 + j2 + (m<<6))] = x[m];
  }
  __builtin_amdgcn_wave_barrier();   // 64-block consumers are the same wave
  // ---- P3 fwd: s=8 ----
  const int j3 = T & 7, g3 = (T>>3)<<6;
  {
    #pragma unroll
    for (int m = 0; m < 8; m++) x[m] = z[ZS4(g3 + j3 + (m<<3))];
    dft8_fwd(x); tw_fwd(x, T3, 8, j3);
    #pragma unroll
    for (int m = 0; m < 8; m++) z[ZS4(g3 + j3 + (m<<3))] = x[m];
  }
  __builtin_amdgcn_wave_barrier();   // 8-block consumers are the same wave
  // ---- P4 fwd: contiguous 8-block, publish spectrum ----
  {
    #pragma unroll
    for (int m = 0; m < 8; m++) x[m] = z[ZS4((T<<3) + m)];
    dft8_fwd(x);                     // x[m] = Z[k], k = m*512 + rev3(T)
    #pragma unroll
    for (int m = 0; m < 8; m++) z[ZS4((T<<3) + m)] = x[m];
  }
  __syncthreads();
  // ---- untangle: V[k] from Z[k], Z[4096-k] (streamed), H tables (r6 formula) ----
  {
    DECL_W16C
    const float2 wbase = wbt[T];
    const int tp = mir[T];           // partner thread (rev3-mirror); mir[0]=0
    const bool t0 = (T == 0);
    const float4* ka4 = (const float4*)(kda + (T<<3));
    const float4* kb4 = (const float4*)(kdb + (T<<3));
    #pragma unroll
    for (int p2 = 0; p2 < 4; p2++) {
      float4 a4 = ka4[p2], b4 = kb4[p2];
      #pragma unroll
      for (int s = 0; s < 2; s++) {
        const int m = 2*p2 + s;
        float2 kdaV = s ? make_float2(a4.z, a4.w) : make_float2(a4.x, a4.y);
        float2 kdbV = s ? make_float2(b4.z, b4.w) : make_float2(b4.x, b4.y);
        const int mp = t0 ? ((8 - m) & 7) : (7 - m);
        float2 Zm = z[ZS4((tp<<3) + mp)];
        float2 Zo = x[m];
        float2 wk = cmulf(wbase, W16C[m]);            // W8192^k
        float Sx = Zo.x + Zm.x, Sy = Zo.y - Zm.y;     // S = Zo + conj(Zm)
        float Dx = Zo.x - Zm.x, Dy = Zo.y + Zm.y;     // D = Zo - conj(Zm)
        float2 t1 = cmulf(wk, make_float2(Dx, Dy));
        float2 Up = make_float2(Sx + t1.y, Sy - t1.x);    // U'  = S - i*t1
        float2 Um = make_float2(Sx - t1.y, -Sy - t1.x);   // U'm = conj(S) - i*conj(t1)
        float2 Yp = cmulf(Up, kdaV);
        float2 Ym = cmulf(Um, kdbV);
        float Pxx = Yp.x + Ym.x, Pyy = Yp.y - Ym.y;
        float Qx  = Yp.x - Ym.x, Qy  = Yp.y + Ym.y;
        float2 t2 = cmulc(make_float2(Qx, Qy), wk);
        x[m] = make_float2(Pxx - t2.y, Pyy + t2.x);       // V = P + i*t2
      }
    }
  }
  __syncthreads();                   // all mirror reads done before overwrite
  // ---- P4 inv: contiguous (no twiddle) ----
  {
    dft8_inv(x);
    #pragma unroll
    for (int m = 0; m < 8; m++) z[ZS4((T<<3) + m)] = x[m];
  }
  __builtin_amdgcn_wave_barrier();
  // ---- P3 inv ----
  {
    #pragma unroll
    for (int m = 0; m < 8; m++) x[m] = z[ZS4(g3 + j3 + (m<<3))];
    tw_inv(x, T3, 8, j3); dft8_inv(x);
    #pragma unroll
    for (int m = 0; m < 8; m++) z[ZS4(g3 + j3 + (m<<3))] = x[m];
  }
  __builtin_amdgcn_wave_barrier();
  // ---- P2 inv ----
  {
    #pragma unroll
    for (int m = 0; m < 8; m++) x[m] = z[ZS4(g2 + j2 + (m<<6))];
    tw_inv(x, T2, 64, j2); dft8_inv(x);
    #pragma unroll
    for (int m = 0; m < 8; m++) z[ZS4(g2 + j2 + (m<<6))] = x[m];
  }
  __syncthreads();
  // ---- P1 inv + unpack store (y[2n],y[2n+1]) = (x.x,x.y), n<2048 only ----
  {
    #pragma unroll
    for (int m = 0; m < 8; m++) x[m] = z[ZS4(T + (m<<9))];
    tw_inv(x, T1, 512, T); dft8_inv(x);
    float2* o2 = (float2*)(out + (size_t)blockIdx.x*LSEQ);
    #pragma unroll
    for (int m = 0; m < 4; m++) o2[T + (m<<9)] = x[m];
  }
}

extern "C" void kernel_launch(void* const* d_in, const int* in_sizes, int n_in,
                              void* d_out, int out_size, void* d_ws, size_t ws_size,
                              hipStream_t stream) {
  const float* u     = (const float*)d_in[0];
  const float* Lre   = (const float*)d_in[1];
  const float* Lim   = (const float*)d_in[2];
  const float* Pre   = (const float*)d_in[3];
  const float* Pim   = (const float*)d_in[4];
  const float* Bre   = (const float*)d_in[5];
  const float* Bim   = (const float*)d_in[6];
  const float* Cri   = (const float*)d_in[7];
  const float* Dp    = (const float*)d_in[8];
  const float* lstep = (const float*)d_in[9];
  float* out = (float*)d_out;

  char* ws = (char*)d_ws;
  float2* a_ws   = (float2*)(ws);             //  32768 B : at_roots (reused as kda later)
  float*  K_ws   = (float*)(ws + 32768);      //  16384 B : K time domain
  float2* kdb_ws = (float2*)(ws + 49152);     //  32768 B : H[4096-k] per position
  float2* H_ws   = (float2*)(ws + 81920);     //  32776 B : half-spectrum H[0..4096]
  float4* T1_ws  = (float4*)(ws + 115072);    //  32768 B : P1 twiddles [4][512]
  float4* T2_ws  = (float4*)(ws + 147840);    //   4096 B : P2 twiddles [4][64]
  float4* T3_ws  = (float4*)(ws + 151936);    //    512 B : P3 twiddles [4][8]
  float2* wb_ws  = (float2*)(ws + 152448);    //   4096 B : W8192^{rev3(t)}
  int*    mir_ws = (int*)(ws + 156544);       //   2048 B : mirror thread table
  float2* kda_ws = a_ws;                      // a dead after ktime; kdmap runs after hspec

  hipLaunchKernelGGL(prep1_kernel, dim3(76),   dim3(256), 0, stream,
                     Lre, Lim, Pre, Pim, Bre, Bim, Cri, lstep, a_ws,
                     T1_ws, T2_ws, T3_ws, wb_ws, mir_ws);
  hipLaunchKernelGGL(ktime_kernel, dim3(1024), dim3(256), 0, stream, a_ws, K_ws);
  hipLaunchKernelGGL(hspec_kernel, dim3(1025), dim3(256), 0, stream, K_ws, H_ws);
  hipLaunchKernelGGL(kdmap_kernel, dim3(16),   dim3(256), 0, stream,
                     H_ws, Dp, kda_ws, kdb_ws);
  hipLaunchKernelGGL(conv4_kernel, dim3(NBH),  dim3(512), 0, stream,
                     u, T1_ws, T2_ws, T3_ws, wb_ws, mir_ws, kda_ws, kdb_ws, out);
}

// Round 18
// 104.597 us; speedup vs baseline: 1.5577x; 1.5577x over previous
//
#include <hip/hip_runtime.h>
#include <math.h>

#define LSEQ 4096
#define MFFT 8192
#define NM   64
#define NBH  4096

__device__ __forceinline__ float2 cmulf(float2 a, float2 b) {
  return make_float2(a.x*b.x - a.y*b.y, a.x*b.y + a.y*b.x);
}
// a * conj(b)
__device__ __forceinline__ float2 cmulc(float2 a, float2 b) {
  return make_float2(a.x*b.x + a.y*b.y, a.y*b.x - a.x*b.y);
}
__device__ __forceinline__ float2 caddf(float2 a, float2 b){ return make_float2(a.x+b.x, a.y+b.y); }
__device__ __forceinline__ float2 csubf(float2 a, float2 b){ return make_float2(a.x-b.x, a.y-b.y); }

// storage swizzle (r6-validated): low4 ^= bits4-7, bits4-7 ^= bits8-11. Bijective; keeps
// every 256-block in place. All pass patterns (strides 1024/128/16/2) at b64 bank floor.
__device__ __forceinline__ int ZS(int i){ return i ^ ((i>>4)&15) ^ (((i>>8)&15)<<4); }

// ---- 8-point DFT, DIF r2 cascade, outputs in natural freq order x[m]=F_m ----
__device__ __forceinline__ void dft8_fwd(float2 x[8]) {
  const float RC = 0.7071067811865476f;
  float2 u0=caddf(x[0],x[4]), v0=csubf(x[0],x[4]);
  float2 u1=caddf(x[1],x[5]), d1=csubf(x[1],x[5]);
  float2 u2=caddf(x[2],x[6]), d2=csubf(x[2],x[6]);
  float2 u3=caddf(x[3],x[7]), d3=csubf(x[3],x[7]);
  float2 v1 = make_float2(RC*(d1.x + d1.y), RC*(d1.y - d1.x));   // *W8^1=(c,-c)
  float2 v2 = make_float2(d2.y, -d2.x);                          // *(-i)
  float2 v3 = make_float2(RC*(d3.y - d3.x), -RC*(d3.x + d3.y));  // *W8^3=(-c,-c)
  float2 p0=caddf(u0,u2), q0=csubf(u0,u2);
  float2 p1=caddf(u1,u3), qt=csubf(u1,u3);
  float2 q1 = make_float2(qt.y, -qt.x);                          // *(-i)
  float2 r0=caddf(v0,v2), s0=csubf(v0,v2);
  float2 r1=caddf(v1,v3), st=csubf(v1,v3);
  float2 s1 = make_float2(st.y, -st.x);                          // *(-i)
  x[0]=caddf(p0,p1); x[4]=csubf(p0,p1);
  x[2]=caddf(q0,q1); x[6]=csubf(q0,q1);
  x[1]=caddf(r0,r1); x[5]=csubf(r0,r1);
  x[3]=caddf(s0,s1); x[7]=csubf(s0,s1);
}
// exact operation-reverse (unnormalized: inv(fwd) = 8*id; total 8192 folded into Kd)
__device__ __forceinline__ void dft8_inv(float2 x[8]) {
  const float RC = 0.7071067811865476f;
  float2 p0=caddf(x[0],x[4]), p1=csubf(x[0],x[4]);
  float2 q0=caddf(x[2],x[6]), q1=csubf(x[2],x[6]);
  float2 r0=caddf(x[1],x[5]), r1=csubf(x[1],x[5]);
  float2 s0=caddf(x[3],x[7]), s1=csubf(x[3],x[7]);
  float2 q1i = make_float2(-q1.y, q1.x);                         // *(+i)
  float2 s1i = make_float2(-s1.y, s1.x);
  float2 u0=caddf(p0,q0), u2=csubf(p0,q0);
  float2 u1=caddf(p1,q1i), u3=csubf(p1,q1i);
  float2 v0=caddf(r0,s0), v2=csubf(r0,s0);
  float2 v1=caddf(r1,s1i), v3=csubf(r1,s1i);
  float2 w1 = make_float2(RC*(v1.x - v1.y), RC*(v1.x + v1.y));   // *conj(W8^1)=(c,c)
  float2 w2 = make_float2(-v2.y, v2.x);                          // *(+i)
  float2 w3 = make_float2(-RC*(v3.x + v3.y), RC*(v3.x - v3.y));  // *conj(W8^3)=(-c,c)
  x[0]=caddf(u0,v0); x[4]=csubf(u0,v0);
  x[1]=caddf(u1,w1); x[5]=csubf(u1,w1);
  x[2]=caddf(u2,w2); x[6]=csubf(u2,w2);
  x[3]=caddf(u3,w3); x[7]=csubf(u3,w3);
}

// table twiddles: T[q*J+j] packs (w_{2q+1}, w_{2q+2}); apply post-DFT (fwd) / pre-DFT conj (inv)
__device__ __forceinline__ void tw_fwd(float2 x[8], const float4* __restrict__ T, int J, int j) {
  float4 a0 = T[j],       a1 = T[J+j];
  x[1]=cmulf(x[1],make_float2(a0.x,a0.y));
  x[2]=cmulf(x[2],make_float2(a0.z,a0.w));
  x[3]=cmulf(x[3],make_float2(a1.x,a1.y));
  x[4]=cmulf(x[4],make_float2(a1.z,a1.w));
  float4 a2 = T[2*J+j],   a3 = T[3*J+j];
  x[5]=cmulf(x[5],make_float2(a2.x,a2.y));
  x[6]=cmulf(x[6],make_float2(a2.z,a2.w));
  x[7]=cmulf(x[7],make_float2(a3.x,a3.y));
}
__device__ __forceinline__ void tw_inv(float2 x[8], const float4* __restrict__ T, int J, int j) {
  float4 a0 = T[j],       a1 = T[J+j];
  x[1]=cmulc(x[1],make_float2(a0.x,a0.y));
  x[2]=cmulc(x[2],make_float2(a0.z,a0.w));
  x[3]=cmulc(x[3],make_float2(a1.x,a1.y));
  x[4]=cmulc(x[4],make_float2(a1.z,a1.w));
  float4 a2 = T[2*J+j],   a3 = T[3*J+j];
  x[5]=cmulc(x[5],make_float2(a2.x,a2.y));
  x[6]=cmulc(x[6],make_float2(a2.z,a2.w));
  x[7]=cmulc(x[7],make_float2(a3.x,a3.y));
}

// W16^m = exp(-2*pi*i*m/16)  (r15-validated)
#define DECL_W16C \
  const float2 W16C[8] = { make_float2(1.f,0.f), \
    make_float2(0.9238795325112867f,-0.3826834323650898f), \
    make_float2(0.7071067811865476f,-0.7071067811865476f), \
    make_float2(0.3826834323650898f,-0.9238795325112867f), \
    make_float2(0.f,-1.f), \
    make_float2(-0.3826834323650898f,-0.9238795325112867f), \
    make_float2(-0.7071067811865476f,-0.7071067811865476f), \
    make_float2(-0.9238795325112867f,-0.3826834323650898f) };

__device__ __forceinline__ float2 W8192e(long long e) {
  double ang = -2.0*M_PI*(double)(e & (MFFT-1))/(double)MFFT;
  return make_float2((float)cos(ang), (float)sin(ang));
}

// ---------------- prep1: MERGED cauchy (blocks 0..63) + twiddle tables (64..82) ----------
// cauchy uses 4 LANES PER k (n-loop split 4 ways + fp64 shfl_xor reduce).
__global__ void prep1_kernel(const float* __restrict__ Lre, const float* __restrict__ Lim,
                             const float* __restrict__ Pre, const float* __restrict__ Pim,
                             const float* __restrict__ Bre, const float* __restrict__ Bim,
                             const float* __restrict__ Cri, const float* __restrict__ lstep,
                             float2* __restrict__ a_out,
                             float4* __restrict__ T1, float4* __restrict__ T2,
                             float4* __restrict__ T3) {
  if (blockIdx.x >= 64) {
    // ---- twiddle tables, one float4 per thread (r15-validated values) ----
    int idx = (blockIdx.x - 64)*blockDim.x + threadIdx.x;
    if (idx < 4096) {                        // T1: stride 1024: w_m = W8192^{j m}
      int q = idx >> 10, j = idx & 1023;
      float2 wa = W8192e((long long)j*(2*q+1));
      float2 wb = W8192e((long long)j*(2*q+2));
      T1[(q<<10)+j] = make_float4(wa.x, wa.y, wb.x, wb.y);
    } else if (idx < 4608) {                 // T2: stride 128: W8192^{8 j m}
      int r = idx - 4096; int q = r >> 7, j = r & 127;
      float2 wa = W8192e(8LL*j*(2*q+1));
      float2 wb = W8192e(8LL*j*(2*q+2));
      T2[(q<<7)+j] = make_float4(wa.x, wa.y, wb.x, wb.y);
    } else if (idx < 4672) {                 // T3: stride 16: W8192^{64 j m}
      int r = idx - 4608; int q = r >> 4, j = r & 15;
      float2 wa = W8192e(64LL*j*(2*q+1));
      float2 wb = W8192e(64LL*j*(2*q+2));
      T3[(q<<4)+j] = make_float4(wa.x, wa.y, wb.x, wb.y);
    }
    return;
  }
  // ---- cauchy: k = 64*block + tid/4, 4 sub-lanes split the n-loop ----
  const int tid = threadIdx.x;
  const int k = (blockIdx.x << 6) + (tid >> 2);
  const int sub = tid & 3;
  double step = exp((double)lstep[0]);
  double ang = -2.0*M_PI*(double)k/(double)LSEQ;
  double wr = cos(ang), wi = sin(ang);
  double nr = 1.0 - wr, ni = -wi;
  double dr = 1.0 + wr, di = wi;
  double dn = dr*dr + di*di;
  double gre = (2.0/step) * (nr*dr + ni*di)/dn;
  double gim = (2.0/step) * (ni*dr - nr*di)/dn;
  double cre = 2.0*dr/dn, cim = -2.0*di/dn;
  double k00r=0,k00i=0,k01r=0,k01i=0,k10r=0,k10i=0,k11r=0,k11i=0;
  for (int n = sub; n < NM; n += 4) {
    double lre = Lre[n], lim = Lim[n];
    double pre = Pre[n], pim = Pim[n];
    double bre = Bre[n], bim = Bim[n];
    double ccr = Cri[2*n], cci = Cri[2*n+1];
    double er = gre - lre, ei = gim - lim;
    double inv = 1.0/(er*er + ei*ei);
    double ir =  er*inv, ii = -ei*inv;
    double v00r = ccr*bre + cci*bim, v00i = ccr*bim - cci*bre;
    double v01r = ccr*pre + cci*pim, v01i = ccr*pim - cci*pre;
    double v10r = pre*bre + pim*bim, v10i = pre*bim - pim*bre;
    double v11r = pre*pre + pim*pim, v11i = 0.0;
    k00r += v00r*ir - v00i*ii;  k00i += v00r*ii + v00i*ir;
    k01r += v01r*ir - v01i*ii;  k01i += v01r*ii + v01i*ir;
    k10r += v10r*ir - v10i*ii;  k10i += v10r*ii + v10i*ir;
    k11r += v11r*ir - v11i*ii;  k11i += v11r*ii + v11i*ir;
  }
  // reduce the 8 accumulators across the 4 sub-lanes (fp64 shfl butterfly)
  #pragma unroll
  for (int d = 1; d <= 2; d <<= 1) {
    k00r += __shfl_xor(k00r, d);  k00i += __shfl_xor(k00i, d);
    k01r += __shfl_xor(k01r, d);  k01i += __shfl_xor(k01i, d);
    k10r += __shfl_xor(k10r, d);  k10i += __shfl_xor(k10i, d);
    k11r += __shfl_xor(k11r, d);  k11i += __shfl_xor(k11i, d);
  }
  if (sub == 0) {
    double numr = k01r*k10r - k01i*k10i, numi = k01r*k10i + k01i*k10r;
    double der = 1.0 + k11r, dei = k11i;
    double dinv = 1.0/(der*der + dei*dei);
    double qr = (numr*der + numi*dei)*dinv;
    double qi = (numi*der - numr*dei)*dinv;
    double tr = k00r - qr, ti = k00i - qi;
    double ar = cre*tr - cim*ti, ai = cre*ti + cim*tr;
    a_out[k] = make_float2((float)ar, (float)ai);
  }
}

// ---------------- prep: K[l] = Re(IDFT_L(a))[l], 64 lanes per output ----------------
__global__ void ktime_kernel(const float2* __restrict__ a, float* __restrict__ K) {
  int lane = threadIdx.x & 63;
  int l = blockIdx.x * (blockDim.x >> 6) + (threadIdx.x >> 6);
  if (l >= LSEQ) return;
  double ang0 = 2.0*M_PI*(double)((l*lane) & (LSEQ-1))/(double)LSEQ;
  double tr = cos(ang0), ti = sin(ang0);
  double ang1 = 2.0*M_PI*(double)(l & 63)/64.0;
  double wr = cos(ang1), wi = sin(ang1);
  double acc = 0.0;
  for (int k = 0; k < 64; k++) {
    float2 ak = a[lane + (k << 6)];
    acc += (double)ak.x*tr - (double)ak.y*ti;
    double ntr = tr*wr - ti*wi;
    ti = tr*wi + ti*wr;
    tr = ntr;
  }
  for (int off = 32; off > 0; off >>= 1) acc += __shfl_down(acc, off);
  if (lane == 0) K[l] = (float)(acc/(double)LSEQ);
}

// ---------------- prep: KdE/KdO = fwd chain(pad(K + D*delta)) / 8192, even/odd split ------
// Runs the IDENTICAL fwd chain as conv8 -> permutation self-consistency.
__global__ void kd8_kernel(const float* __restrict__ K, const float* __restrict__ Dp,
                           const float4* __restrict__ T1, const float4* __restrict__ T2,
                           const float4* __restrict__ T3,
                           float2* __restrict__ KdE, float2* __restrict__ KdO) {
  __shared__ float2 z[MFFT];
  const int t = threadIdx.x;
  float2 x[8];
  // P1: stride 1024, j=t; fold D into K[0] (time domain)
  #pragma unroll
  for (int k = 0; k < 4; k++) {
    float v = K[t + (k<<10)];
    if (t == 0 && k == 0) v += Dp[0];
    x[k] = make_float2(v, 0.f);
  }
  #pragma unroll
  for (int k = 4; k < 8; k++) x[k] = make_float2(0.f, 0.f);
  dft8_fwd(x); tw_fwd(x, T1, 1024, t);
  #pragma unroll
  for (int m = 0; m < 8; m++) z[ZS(t + (m<<10))] = x[m];
  __syncthreads();
  // P2: stride 128
  {
    const int j2 = t & 127, gb2 = (t>>7)<<10;
    int ai[8];
    #pragma unroll
    for (int m = 0; m < 8; m++) ai[m] = ZS(gb2 + j2 + (m<<7));
    #pragma unroll
    for (int m = 0; m < 8; m++) x[m] = z[ai[m]];
    dft8_fwd(x); tw_fwd(x, T2, 128, j2);
    #pragma unroll
    for (int m = 0; m < 8; m++) z[ai[m]] = x[m];
  }
  __syncthreads();
  // P3: stride 16
  {
    const int j3 = t & 15, gb3 = (t>>4)<<7;
    int ai[8];
    #pragma unroll
    for (int m = 0; m < 8; m++) ai[m] = ZS(gb3 + j3 + (m<<4));
    #pragma unroll
    for (int m = 0; m < 8; m++) x[m] = z[ai[m]];
    dft8_fwd(x); tw_fwd(x, T3, 16, j3);
    #pragma unroll
    for (int m = 0; m < 8; m++) z[ai[m]] = x[m];
  }
  __builtin_amdgcn_wave_barrier();      // P3->F4 producers are same-wave (mapping verified)
  // F4: stride 2 (const W16 twiddles) + final r2 via shfl; store scaled spectrum
  {
    DECL_W16C
    const int G4 = t>>1, j1 = t & 1, gb4 = G4<<4;
    #pragma unroll
    for (int m = 0; m < 8; m++) x[m] = z[ZS(gb4 + j1 + (m<<1))];
    dft8_fwd(x);
    #pragma unroll
    for (int m = 1; m < 8; m++) {
      float2 wm = j1 ? W16C[m] : make_float2(1.f, 0.f);
      x[m] = cmulf(x[m], wm);
    }
    const float sc = 1.0f/8192.0f;
    float2* kout = (j1 ? KdO : KdE) + (G4<<3);
    #pragma unroll
    for (int p = 0; p < 8; p++) {
      float ox = __shfl_xor(x[p].x, 1);
      float oy = __shfl_xor(x[p].y, 1);
      float2 v = j1 ? make_float2(ox - x[p].x, oy - x[p].y)
                    : make_float2(x[p].x + ox, x[p].y + oy);
      kout[p] = make_float2(v.x*sc, v.y*sc);
    }
  }
}

// ---------------- main: 2 rows/block, 8192-pt FFT, 1024 thr x 8 elems, radix-8^4 ----------
// r15/r16-VALIDATED BEST: VGPR 60 (<=64 class -> 8 waves/SIMD), zero spill, conv ~100us.
// r17's 32KB/1-row untangle variant hit the 64-reg wall (VGPR=64 + 327MB scratch WRITE,
// conv 182-245us) -- this 2-row/64KB/x[8] structure is the fixed point of the design space.
__global__ __launch_bounds__(1024, 4)
void conv8_kernel(const float* __restrict__ u,
                  const float4* __restrict__ T1, const float4* __restrict__ T2,
                  const float4* __restrict__ T3,
                  const float2* __restrict__ KdE, const float2* __restrict__ KdO,
                  float* __restrict__ out) {
  __shared__ float2 z[MFFT];
  const int t = threadIdx.x;
  const int r0 = blockIdx.x, r1 = blockIdx.x + (NBH/2);
  const float* u0 = u + (size_t)r0*LSEQ;
  const float* u1 = u + (size_t)r1*LSEQ;
  float2 x[8];
  // ---- P1 fwd: stride 1024, j=t ----
  {
    #pragma unroll
    for (int k = 0; k < 4; k++)
      x[k] = make_float2(u0[t + (k<<10)], u1[t + (k<<10)]);
    #pragma unroll
    for (int k = 4; k < 8; k++) x[k] = make_float2(0.f, 0.f);
    dft8_fwd(x); tw_fwd(x, T1, 1024, t);
    #pragma unroll
    for (int m = 0; m < 8; m++) z[ZS(t + (m<<10))] = x[m];
  }
  __syncthreads();
  // ---- P2 fwd: stride 128 ----
  const int j2 = t & 127, gb2 = (t>>7)<<10;
  {
    int ai[8];
    #pragma unroll
    for (int m = 0; m < 8; m++) ai[m] = ZS(gb2 + j2 + (m<<7));
    #pragma unroll
    for (int m = 0; m < 8; m++) x[m] = z[ai[m]];
    dft8_fwd(x); tw_fwd(x, T2, 128, j2);
    #pragma unroll
    for (int m = 0; m < 8; m++) z[ai[m]] = x[m];
  }
  __syncthreads();
  // ---- P3 fwd: stride 16 ----
  const int j3 = t & 15, gb3 = (t>>4)<<7;
  {
    int ai[8];
    #pragma unroll
    for (int m = 0; m < 8; m++) ai[m] = ZS(gb3 + j3 + (m<<4));
    #pragma unroll
    for (int m = 0; m < 8; m++) x[m] = z[ai[m]];
    dft8_fwd(x); tw_fwd(x, T3, 16, j3);
    #pragma unroll
    for (int m = 0; m < 8; m++) z[ai[m]] = x[m];
  }
  __builtin_amdgcn_wave_barrier();   // F4 wave reads [512w,512w+512) written by same wave
  // ---- F4: r8(s=2) + r2-shfl + xKd + r2-shfl-inv + r8i(s=2), all in registers ----
  {
    DECL_W16C
    const int G4 = t>>1, j1 = t & 1, gb4 = G4<<4;
    int ai[8];
    #pragma unroll
    for (int m = 0; m < 8; m++) ai[m] = ZS(gb4 + j1 + (m<<1));
    #pragma unroll
    for (int m = 0; m < 8; m++) x[m] = z[ai[m]];
    dft8_fwd(x);
    #pragma unroll
    for (int m = 1; m < 8; m++) {
      float2 wm = j1 ? W16C[m] : make_float2(1.f, 0.f);
      x[m] = cmulf(x[m], wm);
    }
    // final r2 (pairs = even/odd thread slots) + pointwise xKd, staged 2 kd at a time
    const float4* kp = (const float4*)((j1 ? KdO : KdE) + (G4<<3));
    #pragma unroll
    for (int p2 = 0; p2 < 4; p2++) {
      float4 kq = kp[p2];
      #pragma unroll
      for (int s = 0; s < 2; s++) {
        const int p = 2*p2 + s;
        float2 kd = s ? make_float2(kq.z, kq.w) : make_float2(kq.x, kq.y);
        float ox = __shfl_xor(x[p].x, 1);
        float oy = __shfl_xor(x[p].y, 1);
        float2 v = j1 ? make_float2(ox - x[p].x, oy - x[p].y)   // pos odd: a-b
                      : make_float2(x[p].x + ox, x[p].y + oy);  // pos even: a+b
        x[p] = cmulf(v, kd);
      }
    }
    // r2 inverse (even = s+d, odd = s-d)
    #pragma unroll
    for (int p = 0; p < 8; p++) {
      float ox = __shfl_xor(x[p].x, 1);
      float oy = __shfl_xor(x[p].y, 1);
      x[p] = j1 ? make_float2(ox - x[p].x, oy - x[p].y)
                : make_float2(x[p].x + ox, x[p].y + oy);
    }
    // un-twiddle (conj const) + inverse r8
    #pragma unroll
    for (int m = 1; m < 8; m++) {
      float2 wm = j1 ? W16C[m] : make_float2(1.f, 0.f);
      x[m] = cmulc(x[m], wm);
    }
    dft8_inv(x);
    #pragma unroll
    for (int m = 0; m < 8; m++) z[ai[m]] = x[m];
  }
  __builtin_amdgcn_wave_barrier();
  // ---- P3 inv ----
  {
    int ai[8];
    #pragma unroll
    for (int m = 0; m < 8; m++) ai[m] = ZS(gb3 + j3 + (m<<4));
    #pragma unroll
    for (int m = 0; m < 8; m++) x[m] = z[ai[m]];
    tw_inv(x, T3, 16, j3); dft8_inv(x);
    #pragma unroll
    for (int m = 0; m < 8; m++) z[ai[m]] = x[m];
  }
  __syncthreads();
  // ---- P2 inv ----
  {
    int ai[8];
    #pragma unroll
    for (int m = 0; m < 8; m++) ai[m] = ZS(gb2 + j2 + (m<<7));
    #pragma unroll
    for (int m = 0; m < 8; m++) x[m] = z[ai[m]];
    tw_inv(x, T2, 128, j2); dft8_inv(x);
    #pragma unroll
    for (int m = 0; m < 8; m++) z[ai[m]] = x[m];
  }
  __syncthreads();
  // ---- P1 inv + store (positions >= 4096 discarded) ----
  {
    #pragma unroll
    for (int m = 0; m < 8; m++) x[m] = z[ZS(t + (m<<10))];
    tw_inv(x, T1, 1024, t); dft8_inv(x);
    float* o0 = out + (size_t)r0*LSEQ;
    float* o1 = out + (size_t)r1*LSEQ;
    #pragma unroll
    for (int m = 0; m < 4; m++) {
      int idx = t + (m<<10);
      o0[idx] = x[m].x;
      o1[idx] = x[m].y;
    }
  }
}

extern "C" void kernel_launch(void* const* d_in, const int* in_sizes, int n_in,
                              void* d_out, int out_size, void* d_ws, size_t ws_size,
                              hipStream_t stream) {
  const float* u     = (const float*)d_in[0];
  const float* Lre   = (const float*)d_in[1];
  const float* Lim   = (const float*)d_in[2];
  const float* Pre   = (const float*)d_in[3];
  const float* Pim   = (const float*)d_in[4];
  const float* Bre   = (const float*)d_in[5];
  const float* Bim   = (const float*)d_in[6];
  const float* Cri   = (const float*)d_in[7];
  const float* Dp    = (const float*)d_in[8];
  const float* lstep = (const float*)d_in[9];
  float* out = (float*)d_out;

  char* ws = (char*)d_ws;
  float2* a_ws   = (float2*)(ws);            //  32768 B : at_roots
  float*  K_ws   = (float*)(ws + 32768);     //  16384 B : K time domain
  float2* KdE_ws = (float2*)(ws + 49152);    //  32768 B : spectrum at even in-place pos, /8192
  float2* KdO_ws = (float2*)(ws + 81920);    //  32768 B : odd positions
  float4* T1_ws  = (float4*)(ws + 114688);   //  65536 B : pass-1 twiddles [4][1024]
  float4* T2_ws  = (float4*)(ws + 180224);   //   8192 B : pass-2 twiddles [4][128]
  float4* T3_ws  = (float4*)(ws + 188416);   //   1024 B : pass-3 twiddles [4][16]

  hipLaunchKernelGGL(prep1_kernel,  dim3(83),   dim3(256), 0, stream,
                     Lre, Lim, Pre, Pim, Bre, Bim, Cri, lstep, a_ws,
                     T1_ws, T2_ws, T3_ws);
  hipLaunchKernelGGL(ktime_kernel,  dim3(1024), dim3(256), 0, stream, a_ws, K_ws);
  hipLaunchKernelGGL(kd8_kernel,    dim3(1),    dim3(1024), 0, stream,
                     K_ws, Dp, T1_ws, T2_ws, T3_ws, KdE_ws, KdO_ws);
  hipLaunchKernelGGL(conv8_kernel,  dim3(NBH/2), dim3(1024), 0, stream,
                     u, T1_ws, T2_ws, T3_ws, KdE_ws, KdO_ws, out);
}